// Round 2
// 456.211 us; speedup vs baseline: 1.1527x; 1.1527x over previous
//
#include <hip/hip_runtime.h>

#define C_CLASSES 1000
#define N_SLOTS   128
#define D_DIM     512
#define B_SAMPLES 4096

typedef float v4f __attribute__((ext_vector_type(4)));   // native vec for NT ld/st

// ---------------------------------------------------------------------------
// Kernel A: cls[p] = argmax_k batch_targets[mask[p], k]   (first-index on tie)
// One wave (64 lanes) per sample position p. float4 loads: 1000 = 250 x float4.
// ---------------------------------------------------------------------------
__global__ __launch_bounds__(256) void argmax_kernel(
    const float* __restrict__ targets,   // [B, C]
    const int*   __restrict__ mask,      // [B]
    int*         __restrict__ cls)       // [B]
{
    const int wave = threadIdx.x >> 6;
    const int lane = threadIdx.x & 63;
    const int p = blockIdx.x * 4 + wave;
    if (p >= B_SAMPLES) return;

    const int sample = mask[p];
    const v4f* row4 = (const v4f*)(targets + (long long)sample * C_CLASSES);

    float bestv = -INFINITY;
    int   besti = 0;
    #pragma unroll
    for (int t = 0; t < 4; ++t) {
        const int k4 = lane + t * 64;
        if (k4 < C_CLASSES / 4) {            // 250 float4s, no remainder
            v4f v4 = row4[k4];
            #pragma unroll
            for (int cc = 0; cc < 4; ++cc) { // ascending global index -> strict >
                float v = v4[cc];            // keeps first occurrence per lane
                if (v > bestv) { bestv = v; besti = k4 * 4 + cc; }
            }
        }
    }
    // 64-lane reduction, tie -> smaller index (global first occurrence)
    for (int off = 32; off > 0; off >>= 1) {
        float ov = __shfl_down(bestv, off, 64);
        int   oi = __shfl_down(besti, off, 64);
        if (ov > bestv || (ov == bestv && oi < besti)) { bestv = ov; besti = oi; }
    }
    if (lane == 0) cls[p] = besti;
}

// ---------------------------------------------------------------------------
// Kernel B (fused): per-class simulate + writeback. One 512-thread block
// (8 waves) per class.
//   Phase 1: stage cls[] into LDS (coalesced, whole block).
//   Phase 2: wave 0 builds an ordered match list via ballot compaction (LDS).
//   Phase 3: whole block replays shift+stable-sort per match (block-uniform
//            branches, threads 0..127 own one slot each).
//   Phase 4: all 8 waves stream the 256 KB class tile (float4, nontemporal).
// src encoding: >=0 -> memory row of this class, <0 -> feats row (-(src+1)).
// ---------------------------------------------------------------------------
__global__ __launch_bounds__(512) void sim_write_kernel(
    const float* __restrict__ memory,       // [C, N, D]
    const float* __restrict__ confidences,  // [C, N]
    const float* __restrict__ feats,        // [B, D]
    const int*   __restrict__ bconf,        // [B]
    const int*   __restrict__ mask,         // [B]
    const int*   __restrict__ cls,          // [B]
    float*       __restrict__ out)          // [C, N, D]
{
    const int c    = blockIdx.x;
    const int tid  = threadIdx.x;
    const int lane = tid & 63;
    const int wave = tid >> 6;

    __shared__ int   s_cls[B_SAMPLES];      // 16 KB
    __shared__ int   s_plist[B_SAMPLES];    // 16 KB (worst case: all match)
    __shared__ float s_cf[N_SLOTS];
    __shared__ int   s_src[N_SLOTS];
    __shared__ float s_ncf[N_SLOTS];
    __shared__ int   s_nsrc[N_SLOTS];
    __shared__ float s_conf[N_SLOTS];       // per-chunk prefetched confidences
    __shared__ int   s_feat[N_SLOTS];       // per-chunk prefetched feature idx
    __shared__ int   s_K;

    // ---- Phase 1: stage cls + init per-class state -------------------------
    for (int i = tid; i < B_SAMPLES; i += 512) s_cls[i] = cls[i];
    if (tid < N_SLOTS) {
        s_cf[tid]  = confidences[c * N_SLOTS + tid];
        s_src[tid] = tid;
    }
    __syncthreads();

    // ---- Phase 2: ordered match scan (wave 0, LDS-fed, ~2us) ---------------
    if (wave == 0) {
        int k = 0;
        for (int i = 0; i < B_SAMPLES / 64; ++i) {
            const int p  = i * 64 + lane;
            const int cv = s_cls[p];
            const unsigned long long m = __ballot(cv == c);
            if (cv == c) {
                const int r = __popcll(m & ((1ull << lane) - 1ull));
                s_plist[k + r] = p;           // ascending p by construction
            }
            k += __popcll(m);
        }
        if (lane == 0) s_K = k;
    }
    __syncthreads();
    const int K = s_K;

    // ---- Phase 3: serial replay, chunked conf/feat prefetch ----------------
    for (int base = 0; base < K; base += N_SLOTS) {
        const int chunk = min(N_SLOTS, K - base);
        if (tid < chunk) {                    // parallel gather, hides latency
            const int p   = s_plist[base + tid];
            const int mys = mask[p];
            s_feat[tid] = mys;
            s_conf[tid] = (float)bconf[mys];
        }
        __syncthreads();

        for (int k = 0; k < chunk; ++k) {
            const float conf = s_conf[k];     // LDS broadcast: block-uniform
            const int   feat = s_feat[k];
            const float last = s_cf[N_SLOTS - 1];

            if (conf > last) {                // uniform across the block
                // data shifted by one, confidences NOT shifted, last slot
                // overwritten (faithful to reference).
                if (tid < N_SLOTS) {
                    s_ncf[tid]  = (tid == N_SLOTS - 1) ? conf : s_cf[tid];
                    s_nsrc[tid] = (tid == N_SLOTS - 1) ? -(feat + 1)
                                                       : s_src[tid + 1];
                }
                __syncthreads();

                // stable descending rank == jnp.argsort(-ncf) stable
                float v = 0.f; int sv = 0; int r = 0;
                if (tid < N_SLOTS) {
                    v = s_ncf[tid]; sv = s_nsrc[tid];
                    for (int j = 0; j < N_SLOTS; ++j) {
                        const float vj = s_ncf[j];   // broadcast read
                        r += (vj > v) || (vj == v && j < tid);
                    }
                }
                __syncthreads();
                if (tid < N_SLOTS) { s_cf[r] = v; s_src[r] = sv; }
                __syncthreads();
            }
        }
        __syncthreads();                      // before next chunk prefetch
    }

    // ---- Phase 4: stream the class tile (8 waves x 16 rows x 2 KB) ---------
    #pragma unroll 4
    for (int r = wave; r < N_SLOTS; r += 8) {
        const int s = s_src[r];               // wave-uniform broadcast
        const v4f* sp = (s >= 0)
            ? (const v4f*)(memory + ((long long)c * N_SLOTS + s) * D_DIM)
            : (const v4f*)(feats + (long long)(-(s + 1)) * D_DIM);
        v4f* dp = (v4f*)(out + ((long long)c * N_SLOTS + r) * D_DIM);
        v4f a = __builtin_nontemporal_load(sp + lane);
        v4f b = __builtin_nontemporal_load(sp + lane + 64);
        __builtin_nontemporal_store(a, dp + lane);
        __builtin_nontemporal_store(b, dp + lane + 64);
    }
}

// ---------------------------------------------------------------------------
extern "C" void kernel_launch(void* const* d_in, const int* in_sizes, int n_in,
                              void* d_out, int out_size, void* d_ws, size_t ws_size,
                              hipStream_t stream) {
    const float* memory  = (const float*)d_in[0];  // [C,N,D]
    const float* confid  = (const float*)d_in[1];  // [C,N]
    const float* feats   = (const float*)d_in[2];  // [B,D]
    const float* targets = (const float*)d_in[3];  // [B,C]
    const int*   bconf   = (const int*)d_in[4];    // [B]
    const int*   mask    = (const int*)d_in[5];    // [B]
    float* out = (float*)d_out;

    int* cls = (int*)d_ws;            // [B]

    argmax_kernel<<<(B_SAMPLES + 3) / 4, 256, 0, stream>>>(targets, mask, cls);
    sim_write_kernel<<<C_CLASSES, 512, 0, stream>>>(
        memory, confid, feats, bconf, mask, cls, out);
}

// Round 3
// 454.255 us; speedup vs baseline: 1.1576x; 1.0043x over previous
//
#include <hip/hip_runtime.h>

#define C_CLASSES 1000
#define N_SLOTS   128
#define D_DIM     512
#define B_SAMPLES 4096

typedef float v4f __attribute__((ext_vector_type(4)));   // native vec for NT ld/st

// ---------------------------------------------------------------------------
// Kernel A: cls[p] = argmax_k batch_targets[mask[p], k]   (first-index on tie)
// One wave (64 lanes) per sample position p. float4 loads: 1000 = 250 x float4.
// ---------------------------------------------------------------------------
__global__ __launch_bounds__(256) void argmax_kernel(
    const float* __restrict__ targets,   // [B, C]
    const int*   __restrict__ mask,      // [B]
    int*         __restrict__ cls)       // [B]
{
    const int wave = threadIdx.x >> 6;
    const int lane = threadIdx.x & 63;
    const int p = blockIdx.x * 4 + wave;
    if (p >= B_SAMPLES) return;

    const int sample = mask[p];
    const v4f* row4 = (const v4f*)(targets + (long long)sample * C_CLASSES);

    float bestv = -INFINITY;
    int   besti = 0;
    #pragma unroll
    for (int t = 0; t < 4; ++t) {
        const int k4 = lane + t * 64;
        if (k4 < C_CLASSES / 4) {            // 250 float4s, no remainder
            v4f v4 = row4[k4];
            #pragma unroll
            for (int cc = 0; cc < 4; ++cc) { // ascending global index -> strict >
                float v = v4[cc];            // keeps first occurrence per lane
                if (v > bestv) { bestv = v; besti = k4 * 4 + cc; }
            }
        }
    }
    // 64-lane reduction, tie -> smaller index (global first occurrence)
    for (int off = 32; off > 0; off >>= 1) {
        float ov = __shfl_down(bestv, off, 64);
        int   oi = __shfl_down(besti, off, 64);
        if (ov > bestv || (ov == bestv && oi < besti)) { bestv = ov; besti = oi; }
    }
    if (lane == 0) cls[p] = besti;
}

// ---------------------------------------------------------------------------
// Kernel B (fused): per-class simulate + writeback. One 512-thread block
// (8 waves) per class.
//   Phase 1: 8-wave parallel ordered match scan: wave w scans p in
//            [w*512,(w+1)*512) via ballot compaction into its own s_plist
//            region; 8-element prefix gives global ascending-p order.
//   Phase 2: whole block replays shift+stable-sort per match (block-uniform
//            branches, threads 0..127 own one slot each).
//   Phase 3: all 8 waves stream the 256 KB class tile (float4, nontemporal).
// src encoding: >=0 -> memory row of this class, <0 -> feats row (-(src+1)).
// ---------------------------------------------------------------------------
__global__ __launch_bounds__(512) void sim_write_kernel(
    const float* __restrict__ memory,       // [C, N, D]
    const float* __restrict__ confidences,  // [C, N]
    const float* __restrict__ feats,        // [B, D]
    const int*   __restrict__ bconf,        // [B]
    const int*   __restrict__ mask,         // [B]
    const int*   __restrict__ cls,          // [B]
    float*       __restrict__ out)          // [C, N, D]
{
    const int c    = blockIdx.x;
    const int tid  = threadIdx.x;
    const int lane = tid & 63;
    const int wave = tid >> 6;

    __shared__ int   s_plist[8 * 512];      // 16 KB, per-wave regions
    __shared__ int   s_wcnt[8];
    __shared__ int   s_pref[9];
    __shared__ float s_cf[N_SLOTS];
    __shared__ int   s_src[N_SLOTS];
    __shared__ float s_ncf[N_SLOTS];
    __shared__ int   s_nsrc[N_SLOTS];
    __shared__ float s_conf[N_SLOTS];       // per-chunk prefetched confidences
    __shared__ int   s_feat[N_SLOTS];       // per-chunk prefetched feature idx

    // ---- Phase 1: parallel ordered match scan (all 8 waves, global reads) --
    if (tid < N_SLOTS) {
        s_cf[tid]  = confidences[c * N_SLOTS + tid];
        s_src[tid] = tid;
    }
    {
        int k = 0;
        #pragma unroll
        for (int i = 0; i < 8; ++i) {
            const int p  = wave * 512 + i * 64 + lane;   // coalesced, L2-hot
            const int cv = cls[p];
            const unsigned long long m = __ballot(cv == c);
            if (cv == c) {
                const int r = __popcll(m & ((1ull << lane) - 1ull));
                s_plist[wave * 512 + k + r] = p;         // ascending p per wave
            }
            k += __popcll(m);
        }
        if (lane == 0) s_wcnt[wave] = k;
    }
    __syncthreads();
    if (tid == 0) {
        int acc = 0;
        #pragma unroll
        for (int w = 0; w < 8; ++w) { s_pref[w] = acc; acc += s_wcnt[w]; }
        s_pref[8] = acc;
    }
    __syncthreads();
    const int K = s_pref[8];

    // ---- Phase 2: serial replay, chunked conf/feat prefetch ----------------
    for (int base = 0; base < K; base += N_SLOTS) {
        const int chunk = min(N_SLOTS, K - base);
        if (tid < chunk) {                    // parallel gather, hides latency
            const int g = base + tid;
            int w = 0;
            #pragma unroll
            for (int u = 1; u < 8; ++u) w += (g >= s_pref[u]);
            const int p   = s_plist[w * 512 + (g - s_pref[w])];
            const int mys = mask[p];
            s_feat[tid] = mys;
            s_conf[tid] = (float)bconf[mys];
        }
        __syncthreads();

        for (int k = 0; k < chunk; ++k) {
            const float conf = s_conf[k];     // LDS broadcast: block-uniform
            const int   feat = s_feat[k];
            const float last = s_cf[N_SLOTS - 1];

            if (conf > last) {                // uniform across the block
                // data shifted by one, confidences NOT shifted, last slot
                // overwritten (faithful to reference).
                if (tid < N_SLOTS) {
                    s_ncf[tid]  = (tid == N_SLOTS - 1) ? conf : s_cf[tid];
                    s_nsrc[tid] = (tid == N_SLOTS - 1) ? -(feat + 1)
                                                       : s_src[tid + 1];
                }
                __syncthreads();

                // stable descending rank == jnp.argsort(-ncf) stable
                float v = 0.f; int sv = 0; int r = 0;
                if (tid < N_SLOTS) {
                    v = s_ncf[tid]; sv = s_nsrc[tid];
                    for (int j = 0; j < N_SLOTS; ++j) {
                        const float vj = s_ncf[j];   // broadcast read
                        r += (vj > v) || (vj == v && j < tid);
                    }
                }
                __syncthreads();
                if (tid < N_SLOTS) { s_cf[r] = v; s_src[r] = sv; }
                __syncthreads();
            }
        }
        __syncthreads();                      // before next chunk prefetch
    }

    // ---- Phase 3: stream the class tile (8 waves x 16 rows x 2 KB) ---------
    #pragma unroll 4
    for (int r = wave; r < N_SLOTS; r += 8) {
        const int s = s_src[r];               // wave-uniform broadcast
        const v4f* sp = (s >= 0)
            ? (const v4f*)(memory + ((long long)c * N_SLOTS + s) * D_DIM)
            : (const v4f*)(feats + (long long)(-(s + 1)) * D_DIM);
        v4f* dp = (v4f*)(out + ((long long)c * N_SLOTS + r) * D_DIM);
        v4f a = __builtin_nontemporal_load(sp + lane);
        v4f b = __builtin_nontemporal_load(sp + lane + 64);
        __builtin_nontemporal_store(a, dp + lane);
        __builtin_nontemporal_store(b, dp + lane + 64);
    }
}

// ---------------------------------------------------------------------------
extern "C" void kernel_launch(void* const* d_in, const int* in_sizes, int n_in,
                              void* d_out, int out_size, void* d_ws, size_t ws_size,
                              hipStream_t stream) {
    const float* memory  = (const float*)d_in[0];  // [C,N,D]
    const float* confid  = (const float*)d_in[1];  // [C,N]
    const float* feats   = (const float*)d_in[2];  // [B,D]
    const float* targets = (const float*)d_in[3];  // [B,C]
    const int*   bconf   = (const int*)d_in[4];    // [B]
    const int*   mask    = (const int*)d_in[5];    // [B]
    float* out = (float*)d_out;

    int* cls = (int*)d_ws;            // [B]

    argmax_kernel<<<(B_SAMPLES + 3) / 4, 256, 0, stream>>>(targets, mask, cls);
    sim_write_kernel<<<C_CLASSES, 512, 0, stream>>>(
        memory, confid, feats, bconf, mask, cls, out);
}